// Round 5
// baseline (675.374 us; speedup 1.0000x reference)
//
#include <hip/hip_runtime.h>
#include <math.h>

#define BB 8192
#define TT 60
#define NU 100
#define NI 7

typedef float v2f __attribute__((ext_vector_type(2)));

// lane l (<50) owns unit pair (2l, 2l+1); weights held as 100 v2f registers
// -> v_pk_fma_f32 does both units' MACs in one instruction.
// R5: weights are PINNED into arch VGPRs via no-op asm ("+v") each loop
// iteration — R2-R4 counters (VGPR_Count=120..124, ~610 instr/step) show the
// allocator was keeping them in AGPRs and paying a v_accvgpr_read shuttle
// every step (VOP3P can't source AGPRs).
#define FOR50(M) M(0) M(1) M(2) M(3) M(4) M(5) M(6) M(7) M(8) M(9) \
  M(10) M(11) M(12) M(13) M(14) M(15) M(16) M(17) M(18) M(19) \
  M(20) M(21) M(22) M(23) M(24) M(25) M(26) M(27) M(28) M(29) \
  M(30) M(31) M(32) M(33) M(34) M(35) M(36) M(37) M(38) M(39) \
  M(40) M(41) M(42) M(43) M(44) M(45) M(46) M(47) M(48) M(49)

// weight decls: wA_sl = column 2*sl for both owned units; wB_sl = column 2*sl+1
// (mutable so "+v" asm pinning is legal)
#define DECLW(sl) \
  v2f wA_##sl = { W_rec[uao + 2*(sl)],     W_rec[ubo + 2*(sl)]     }; \
  v2f wB_##sl = { W_rec[uao + 2*(sl) + 1], W_rec[ubo + 2*(sl) + 1] };

#define RL(v,l) __int_as_float(__builtin_amdgcn_readlane(__float_as_int(v), l))

// MAC: broadcast y_{2sl} (lane sl, comp x) and y_{2sl+1} (lane sl, comp y),
// packed-FMA into one of 4 accumulator chains (literal sl folds the branch).
#define MAC(sl) { \
  const float ya = RL(yy.x, sl); \
  const float yb = RL(yy.y, sl); \
  if ((sl) & 1) { accB0 += ya * wA_##sl; accB1 += yb * wB_##sl; } \
  else          { accA0 += ya * wA_##sl; accA1 += yb * wB_##sl; } }

// DPP add-reduce step: part += dpp_move(part, ctrl) (pure VALU, no LDS)
#define DPPADD(ctrl, rmask) { \
  const int _t = __builtin_amdgcn_update_dpp(0, __float_as_int(part), (ctrl), (rmask), 0xf, false); \
  part += __int_as_float(_t); }

// arch-VGPR pin: 25 v2f read-write operands per asm block (stay under
// inline-asm operand limits); placed inside the t-loop so the weights must
// be live in arch VGPRs every iteration.
#define PINA(sl) p##sl:
#define PIN_BLOCK_A0 asm volatile("" : \
  "+v"(wA_0),"+v"(wA_1),"+v"(wA_2),"+v"(wA_3),"+v"(wA_4),"+v"(wA_5), \
  "+v"(wA_6),"+v"(wA_7),"+v"(wA_8),"+v"(wA_9),"+v"(wA_10),"+v"(wA_11), \
  "+v"(wA_12),"+v"(wA_13),"+v"(wA_14),"+v"(wA_15),"+v"(wA_16),"+v"(wA_17), \
  "+v"(wA_18),"+v"(wA_19),"+v"(wA_20),"+v"(wA_21),"+v"(wA_22),"+v"(wA_23), \
  "+v"(wA_24));
#define PIN_BLOCK_A1 asm volatile("" : \
  "+v"(wA_25),"+v"(wA_26),"+v"(wA_27),"+v"(wA_28),"+v"(wA_29),"+v"(wA_30), \
  "+v"(wA_31),"+v"(wA_32),"+v"(wA_33),"+v"(wA_34),"+v"(wA_35),"+v"(wA_36), \
  "+v"(wA_37),"+v"(wA_38),"+v"(wA_39),"+v"(wA_40),"+v"(wA_41),"+v"(wA_42), \
  "+v"(wA_43),"+v"(wA_44),"+v"(wA_45),"+v"(wA_46),"+v"(wA_47),"+v"(wA_48), \
  "+v"(wA_49));
#define PIN_BLOCK_B0 asm volatile("" : \
  "+v"(wB_0),"+v"(wB_1),"+v"(wB_2),"+v"(wB_3),"+v"(wB_4),"+v"(wB_5), \
  "+v"(wB_6),"+v"(wB_7),"+v"(wB_8),"+v"(wB_9),"+v"(wB_10),"+v"(wB_11), \
  "+v"(wB_12),"+v"(wB_13),"+v"(wB_14),"+v"(wB_15),"+v"(wB_16),"+v"(wB_17), \
  "+v"(wB_18),"+v"(wB_19),"+v"(wB_20),"+v"(wB_21),"+v"(wB_22),"+v"(wB_23), \
  "+v"(wB_24));
#define PIN_BLOCK_B1 asm volatile("" : \
  "+v"(wB_25),"+v"(wB_26),"+v"(wB_27),"+v"(wB_28),"+v"(wB_29),"+v"(wB_30), \
  "+v"(wB_31),"+v"(wB_32),"+v"(wB_33),"+v"(wB_34),"+v"(wB_35),"+v"(wB_36), \
  "+v"(wB_37),"+v"(wB_38),"+v"(wB_39),"+v"(wB_40),"+v"(wB_41),"+v"(wB_42), \
  "+v"(wB_43),"+v"(wB_44),"+v"(wB_45),"+v"(wB_46),"+v"(wB_47),"+v"(wB_48), \
  "+v"(wB_49));

__global__ __launch_bounds__(256, 2)
void drr_kernel(const float* __restrict__ y0,
                const float* __restrict__ noise,
                const int*   __restrict__ stim_idx,
                const int*   __restrict__ rew_idx,
                const int*   __restrict__ instr_in,
                const float* __restrict__ W_in_raw,
                const float* __restrict__ W_rec,
                const float* __restrict__ b_rec,
                const float* __restrict__ w_out,
                const float* __restrict__ b_out,
                float* __restrict__ out)
{
    const int lane  = threadIdx.x & 63;
    const int wid   = threadIdx.x >> 6;
    const int trial = blockIdx.x * 4 + wid;

    const bool act = (lane < 50);              // active unit-pair lanes
    const int  la  = act ? lane : 49;          // clamped
    const int  ua  = 2 * la;                   // first unit
    const int  uao = ua * NU;
    const int  ubo = uao + NU;                 // second unit's row

    // per-trial scalars (wave-uniform)
    const int  stim    = stim_idx[trial];
    const int  rew     = rew_idx[trial];
    const bool is_rew  = (stim == rew);
    const bool instr_b = (instr_in[trial] > 0);

    // 100 v2f weight registers (200 arch VGPRs), even-aligned pairs
    FOR50(DECLW)

    // W_in columns (abs applied), packed per unit pair
    const v2f wi6 = { fabsf(W_in_raw[ua * NI + 6]),    fabsf(W_in_raw[(ua+1) * NI + 6]) };
    const v2f wis = { fabsf(W_in_raw[ua * NI + stim]), fabsf(W_in_raw[(ua+1) * NI + stim]) };
    const v2f wr  = { fabsf(W_in_raw[ua * NI + 4]),    fabsf(W_in_raw[(ua+1) * NI + 4]) };
    const v2f wl  = { fabsf(W_in_raw[ua * NI + 5]),    fabsf(W_in_raw[(ua+1) * NI + 5]) };
    const v2f br  = { b_rec[ua], b_rec[ua + 1] };
    const v2f wo  = act ? (v2f){ w_out[ua], w_out[ua + 1] } : (v2f){ 0.0f, 0.0f };
    const float bo = b_out[0];

    const v2f* y0v = (const v2f*)(y0 + trial * NU);
    v2f yy = y0v[la];

    const float NS = 0.09486832980505138f; // 0.15 * sqrt(2*0.2)

    bool licked = false, instr_fired = false;
    int  lick_t = TT + 1;

    const float* nbase = noise + trial * (TT * NU);
    v2f en = ((const v2f*)nbase)[la];          // t=0 prefetch (8B load)

    // output section pointers (flat tuple order)
    float* uout  = out;                        // B*T*7
    float* tout  = out  + BB * TT * NI;        // B*T
    float* rout  = tout + BB * TT;             // B*T
    float* lout  = rout + BB * TT;             // B
    float* dout  = lout + BB;                  // B
    float* zout  = dout + BB;                  // B*T
    float* yfout = zout + BB * TT;             // B*100

    for (int t = 0; t < TT; ++t) {
        // pin all 100 weight v2fs into arch VGPRs for this iteration
        PIN_BLOCK_A0 PIN_BLOCK_A1 PIN_BLOCK_B0 PIN_BLOCK_B1

        const v2f e = en;
        if (t < TT - 1)
            en = ((const v2f*)(nbase + (t + 1) * NU))[la];

        const float sm = (t >= 10 && t < 15) ? 1.0f : 0.0f;  // stim_mask
        const float rm = (t >= 20 && t < 35) ? 1.0f : 0.0f;  // resp_mask

        // reward routing (state from previous step), wave-uniform
        const bool delivered    = instr_fired || (licked && is_rew);
        const bool fire         = instr_b && !delivered && (t == 30);
        instr_fired             = instr_fired || fire;
        const bool instr_active = instr_fired && (t >= 30) && (t < 35);
        const bool lick_dyn     = licked && (t > lick_t) && (t < lick_t + 5);
        const float a_rew  = (instr_active ? 1.0f : 0.0f) + ((lick_dyn && is_rew) ? 1.0f : 0.0f);
        const float a_lick = lick_dyn ? 1.0f : 0.0f;

        v2f accA0 = br + rm * wi6 + sm * wis + a_rew * wr + a_lick * wl + NS * e;
        v2f accA1 = { 0.0f, 0.0f };
        v2f accB0 = { 0.0f, 0.0f };
        v2f accB1 = { 0.0f, 0.0f };

        FOR50(MAC)   // 100 readlane + 100 pk_fma

        const v2f pre = (accA0 + accA1) + (accB0 + accB1);
        const v2f prer = { fmaxf(pre.x, 0.0f), fmaxf(pre.y, 0.0f) };
        yy = 0.8f * yy + 0.2f * prer;

        // z = sigmoid(y . w_out + b_out) — DPP wave64 reduction (no LDS)
        float part = yy.x * wo.x + yy.y * wo.y;
        DPPADD(0x111, 0xf)   // row_shr:1
        DPPADD(0x112, 0xf)   // row_shr:2
        DPPADD(0x114, 0xf)   // row_shr:4
        DPPADD(0x118, 0xf)   // row_shr:8
        DPPADD(0x142, 0xa)   // row_bcast:15 -> rows 1,3
        DPPADD(0x143, 0xc)   // row_bcast:31 -> rows 2,3
        const float x = RL(part, 63) + bo;     // uniform via SGPR
        const float z = 1.0f / (1.0f + expf(-x));

        const bool in_resp = (t >= 20) && (t < 35);
        const bool trig    = in_resp && !licked && (z > 0.5f);
        if (trig) lick_t = t;          // wave-uniform
        licked = licked || trig;
        const bool u5 = licked && (t >= lick_t) && (t < lick_t + 5);
        const bool u4 = instr_active || (u5 && is_rew);

        // per-step outputs
        const int bt = trial * TT + t;
        if (lane < NI) {
            float uv = 0.0f;
            if (lane == stim) uv = sm;                 // stim in [0,4)
            if (lane == 4)    uv = u4 ? 1.0f : 0.0f;
            if (lane == 5)    uv = u5 ? 1.0f : 0.0f;
            if (lane == 6)    uv = rm;
            uout[bt * NI + lane] = uv;
        } else if (lane == 8) {
            tout[bt] = is_rew ? rm : 0.0f;
        } else if (lane == 9) {
            rout[bt] = rm;
        } else if (lane == 10) {
            zout[bt] = z;
        }
    }

    if (lane == 0) {
        lout[trial] = licked ? 1.0f : 0.0f;
        dout[trial] = (instr_fired || (licked && is_rew)) ? 1.0f : 0.0f;
    }
    if (act)
        ((v2f*)(yfout + trial * NU))[la] = yy;   // 8B store, units 2l/2l+1
}

extern "C" void kernel_launch(void* const* d_in, const int* in_sizes, int n_in,
                              void* d_out, int out_size, void* d_ws, size_t ws_size,
                              hipStream_t stream) {
    const float* y0       = (const float*)d_in[0];
    const float* noise    = (const float*)d_in[1];
    const int*   stim     = (const int*)  d_in[2];
    const int*   rew      = (const int*)  d_in[3];
    const int*   instr    = (const int*)  d_in[4];
    const float* W_in_raw = (const float*)d_in[5];
    const float* W_rec    = (const float*)d_in[6];
    const float* b_rec    = (const float*)d_in[7];
    const float* w_out    = (const float*)d_in[8];
    const float* b_out    = (const float*)d_in[9];
    float* out = (float*)d_out;

    drr_kernel<<<BB / 4, 256, 0, stream>>>(y0, noise, stim, rew, instr,
                                           W_in_raw, W_rec, b_rec, w_out, b_out, out);
}